// Round 5
// baseline (221.461 us; speedup 1.0000x reference)
//
#include <hip/hip_runtime.h>
#include <hip/hip_bf16.h>
#include <stdint.h>

#define D_DIM 1024
#define B_DIM 8
#define S_DIM 1024

typedef __bf16 bf16;
typedef __bf16 bf16x4 __attribute__((ext_vector_type(4)));
typedef __bf16 bf16x8 __attribute__((ext_vector_type(8)));
typedef float floatx4 __attribute__((ext_vector_type(4)));

__device__ __forceinline__ void async_copy16(const void* g, void* l) {
    __builtin_amdgcn_global_load_lds(
        (const __attribute__((address_space(1))) void*)g,
        (__attribute__((address_space(3))) void*)l, 16, 0, 0);
}

// ---------------------------------------------------------------------------
// Prep kernel (R3-verified): blocks [0,4096) cast head/dep fp32->bf16 +
// W-projection (one wave per row); blocks [4096,4352) cast U fp32->bf16.
// ---------------------------------------------------------------------------
__global__ __launch_bounds__(256) void prep_kernel(
    const float* __restrict__ head, const float* __restrict__ dep,
    const float* __restrict__ U, const float* __restrict__ edge_W,
    bf16* __restrict__ head_b, bf16* __restrict__ dep_b,
    bf16* __restrict__ U_b,
    float* __restrict__ s_head, float* __restrict__ s_dep)
{
    int blk  = blockIdx.x;
    int wid  = threadIdx.x >> 6;
    int lane = threadIdx.x & 63;

    if (blk < 4096) {
        int row = blk * 4 + wid;

        const float* src;
        bf16* dst;
        const float* w;
        float* sout;
        if (row < B_DIM * S_DIM) {
            src  = head   + (size_t)row * D_DIM;
            dst  = head_b + (size_t)row * D_DIM;
            w    = edge_W;
            sout = s_head + row;
        } else {
            int r = row - B_DIM * S_DIM;
            src  = dep   + (size_t)r * D_DIM;
            dst  = dep_b + (size_t)r * D_DIM;
            w    = edge_W + D_DIM;
            sout = s_dep + r;
        }
        float d = 0.0f;
        #pragma unroll
        for (int it = 0; it < 4; ++it) {
            int idx = it * 64 + lane;
            float4 v  = ((const float4*)src)[idx];
            float4 wv = ((const float4*)w)[idx];
            bf16x4 o;
            o[0] = (bf16)v.x; o[1] = (bf16)v.y; o[2] = (bf16)v.z; o[3] = (bf16)v.w;
            ((bf16x4*)dst)[idx] = o;
            d += v.x * wv.x + v.y * wv.y + v.z * wv.z + v.w * wv.w;
        }
        #pragma unroll
        for (int off = 32; off > 0; off >>= 1)
            d += __shfl_down(d, off, 64);
        if (lane == 0) *sout = d;
    } else {
        int row = (blk - 4096) * 4 + wid;
        const float* src = U   + (size_t)row * D_DIM;
        bf16*        dst = U_b + (size_t)row * D_DIM;
        #pragma unroll
        for (int it = 0; it < 4; ++it) {
            int idx = it * 64 + lane;
            float4 v = ((const float4*)src)[idx];
            bf16x4 o;
            o[0] = (bf16)v.x; o[1] = (bf16)v.y; o[2] = (bf16)v.z; o[3] = (bf16)v.w;
            ((bf16x4*)dst)[idx] = o;
        }
    }
}

// ---------------------------------------------------------------------------
// R1-verified GEMM core: C += A[128xK] * Bt[128xK]^T tile, BK=64, 512 thr
// (8 waves 2Mx4N, per-wave 64x32 = acc[4][2]). global_load_lds width-16
// staging with XOR-swizzled source columns -> conflict-free ds_read_b128.
// ---------------------------------------------------------------------------
__device__ __forceinline__ void gemm_core(
    const bf16* __restrict__ Ab, const bf16* __restrict__ Bb,
    bf16* As, bf16* Bs, floatx4 (&acc)[4][2],
    int wid, int lane, int quad, int l16, int wr, int wc)
{
    for (int k0 = 0; k0 < D_DIM; k0 += 64) {
        #pragma unroll
        for (int it = 0; it < 2; ++it) {
            int g  = wid * 128 + it * 64 + lane;
            int r  = g >> 3;
            int cg = (g & 7) ^ (r & 7);              // XOR swizzle
            int ldsoff = (wid * 128 + it * 64) * 8;  // wave-uniform base
            async_copy16(Ab + (size_t)r * D_DIM + k0 + cg * 8, &As[ldsoff]);
            async_copy16(Bb + (size_t)r * D_DIM + k0 + cg * 8, &Bs[ldsoff]);
        }
        __syncthreads();   // staging complete (vmcnt drain at barrier)

        #pragma unroll
        for (int kk = 0; kk < 64; kk += 32) {
            bf16x8 a[4], b[2];
            #pragma unroll
            for (int mt = 0; mt < 4; ++mt) {
                int row  = wr * 64 + mt * 16 + l16;
                int slot = ((kk >> 3) + quad) ^ (row & 7);
                a[mt] = *(const bf16x8*)&As[row * 64 + slot * 8];
            }
            #pragma unroll
            for (int nt = 0; nt < 2; ++nt) {
                int row  = wc * 32 + nt * 16 + l16;
                int slot = ((kk >> 3) + quad) ^ (row & 7);
                b[nt] = *(const bf16x8*)&Bs[row * 64 + slot * 8];
            }
            __builtin_amdgcn_s_setprio(1);
            #pragma unroll
            for (int mt = 0; mt < 4; ++mt)
                #pragma unroll
                for (int nt = 0; nt < 2; ++nt)
                    acc[mt][nt] = __builtin_amdgcn_mfma_f32_16x16x32_bf16(
                        a[mt], b[nt], acc[mt][nt], 0, 0, 0);
            __builtin_amdgcn_s_setprio(0);
        }
        __syncthreads();   // all reads done before next-iter staging
    }
}

// ---------------------------------------------------------------------------
// Fused GEMM1 + grid-barrier + GEMM2 (one kernel => per-kernel counters
// finally visible: this dispatch is ~60-75 us > the 43 us harness fills).
//
// 512 blocks x 512 threads, exactly 2 blocks/CU co-resident
// (16 waves/CU, VGPR <= 128 via launch_bounds, LDS 32 KB).
// XCD-chunk swizzle (lin%8 = XCD heuristic): XCD k gets swz in [64k,64k+64).
//   Phase 1 decode (bx=swz&7, by=swz>>3): XCD k computes tmpD batch k
//     (dep_b batch k 2MB + U_b 2MB = 4MB = its L2). Plain stores keep
//     tmpD in L2.
//   Phase 2 decode (bx=swz&7, by=(swz>>3)&7, bz=swz>>6): XCD k consumes
//     head_b batch k + tmpD batch k (L2-hot).
// Grid barrier: syncthreads + threadfence + device-scope atomic arrive/spin
// + threadfence + syncthreads (canonical release/acquire pattern; correct
// regardless of the XCD mapping heuristic).
// ---------------------------------------------------------------------------
__global__ __launch_bounds__(512, 4) void gemm_fused(
    const bf16* __restrict__ dep_b, const bf16* __restrict__ U_b,
    const bf16* __restrict__ head_b,
    bf16* __restrict__ tmpD, float* __restrict__ out,
    const float* __restrict__ s_head, const float* __restrict__ s_dep,
    const float* __restrict__ edge_b, int* __restrict__ bar)
{
    __shared__ bf16 As[128 * 64];
    __shared__ bf16 Bs[128 * 64];

    int tid  = threadIdx.x;
    int wid  = tid >> 6;
    int lane = tid & 63;
    int quad = lane >> 4;
    int l16  = lane & 15;
    int wr   = wid >> 2;   // 0..1
    int wc   = wid & 3;    // 0..3

    int lin = blockIdx.x;                    // 0..511
    int swz = (lin & 7) * 64 + (lin >> 3);   // bijective XCD-chunk

    // ---------------- Phase 1: tmpD = dep_b @ U_b^T ----------------
    {
        int bx = swz & 7;        // N-tile (U rows)
        int by = swz >> 3;       // 0..63 M-tile (dep rows)
        int tile_m = by * 128;
        int tile_n = bx * 128;
        const bf16* Ab = dep_b + (size_t)tile_m * D_DIM;
        const bf16* Bb = U_b   + (size_t)tile_n * D_DIM;

        floatx4 zero = {0.0f, 0.0f, 0.0f, 0.0f};
        floatx4 acc[4][2];
        #pragma unroll
        for (int i = 0; i < 4; ++i)
            #pragma unroll
            for (int j = 0; j < 2; ++j) acc[i][j] = zero;

        gemm_core(Ab, Bb, As, Bs, acc, wid, lane, quad, l16, wr, wc);

        int row0 = tile_m + wr * 64;
        int col0 = tile_n + wc * 32;
        #pragma unroll
        for (int mt = 0; mt < 4; ++mt)
            #pragma unroll
            for (int r = 0; r < 4; ++r) {
                int row = row0 + mt * 16 + quad * 4 + r;
                #pragma unroll
                for (int nt = 0; nt < 2; ++nt) {
                    int col = col0 + nt * 16 + l16;
                    // plain store -> stays in this XCD's L2 for phase 2
                    tmpD[(size_t)row * D_DIM + col] = (bf16)acc[mt][nt][r];
                }
            }
    }

    // ---------------- grid barrier (all 512 blocks) ----------------
    __syncthreads();
    if (tid == 0) {
        __threadfence();                       // release: publish tmpD
        atomicAdd(bar, 1);                     // device-scope (m20)
        while (atomicAdd(bar, 0) < 512)
            __builtin_amdgcn_s_sleep(8);
        __threadfence();                       // acquire
    }
    __syncthreads();

    // ---------- Phase 2: out = head_b @ tmpD^T + s_head + s_dep + b ----------
    {
        int bx = swz & 7;          // tmpD j-tile
        int by = (swz >> 3) & 7;   // head i-tile
        int bz = swz >> 6;         // batch (== XCD under the heuristic)
        int tile_m = by * 128;
        int tile_n = bx * 128;
        const bf16* Ab = head_b + (size_t)bz * S_DIM * D_DIM + (size_t)tile_m * D_DIM;
        const bf16* Bb = tmpD   + (size_t)bz * S_DIM * D_DIM + (size_t)tile_n * D_DIM;

        floatx4 zero = {0.0f, 0.0f, 0.0f, 0.0f};
        floatx4 acc[4][2];
        #pragma unroll
        for (int i = 0; i < 4; ++i)
            #pragma unroll
            for (int j = 0; j < 2; ++j) acc[i][j] = zero;

        gemm_core(Ab, Bb, As, Bs, acc, wid, lane, quad, l16, wr, wc);

        float b0 = edge_b[0];
        const float* srow = s_head + (size_t)bz * S_DIM;
        const float* scol = s_dep  + (size_t)bz * S_DIM;
        float* Cf = out + (size_t)bz * S_DIM * S_DIM;
        int row0 = tile_m + wr * 64;
        int col0 = tile_n + wc * 32;
        #pragma unroll
        for (int mt = 0; mt < 4; ++mt)
            #pragma unroll
            for (int r = 0; r < 4; ++r) {
                int row = row0 + mt * 16 + quad * 4 + r;
                float sh = srow[row] + b0;
                #pragma unroll
                for (int nt = 0; nt < 2; ++nt) {
                    int col = col0 + nt * 16 + l16;
                    __builtin_nontemporal_store(acc[mt][nt][r] + sh + scol[col],
                                                &Cf[(size_t)row * S_DIM + col]);
                }
            }
    }
}

// ---------------------------------------------------------------------------
// Chain: prep (cast + projections) -> fused {GEMM1, grid-bar, GEMM2}.
//   tmpD[b,j,d] = sum_k dep[b,j,k] * U[d,k]
//   out[b,i,j]  = sum_d head[b,i,d] * tmpD[b,j,d] + s_head + s_dep + bias
// ---------------------------------------------------------------------------
extern "C" void kernel_launch(void* const* d_in, const int* in_sizes, int n_in,
                              void* d_out, int out_size, void* d_ws, size_t ws_size,
                              hipStream_t stream) {
    const float* head   = (const float*)d_in[0];
    const float* dep    = (const float*)d_in[1];
    const float* edge_U = (const float*)d_in[2];
    const float* edge_W = (const float*)d_in[3];
    const float* edge_b = (const float*)d_in[4];
    float* out = (float*)d_out;

    char* ws = (char*)d_ws;
    const size_t nBSD = (size_t)B_DIM * S_DIM * D_DIM;

    bf16*  head_b = (bf16*)ws;  ws += nBSD * sizeof(bf16);
    bf16*  dep_b  = (bf16*)ws;  ws += nBSD * sizeof(bf16);
    bf16*  U_b    = (bf16*)ws;  ws += (size_t)D_DIM * D_DIM * sizeof(bf16);
    bf16*  tmpD   = (bf16*)ws;  ws += nBSD * sizeof(bf16);
    float* s_head = (float*)ws; ws += (size_t)B_DIM * S_DIM * sizeof(float);
    float* s_dep  = (float*)ws; ws += (size_t)B_DIM * S_DIM * sizeof(float);
    int*   bar    = (int*)ws;   ws += 16;

    // zero the barrier counter (workspace arrives poisoned)
    hipMemsetAsync(bar, 0, sizeof(int), stream);

    // 1. fused cast+projection (4096 blocks) and U-cast (256 blocks)
    prep_kernel<<<4096 + 256, 256, 0, stream>>>(
        head, dep, edge_U, edge_W, head_b, dep_b, U_b, s_head, s_dep);

    // 2. fused GEMM1 + grid-barrier + GEMM2 (512 blocks, 2/CU co-resident)
    gemm_fused<<<512, 512, 0, stream>>>(
        dep_b, U_b, head_b, tmpD, out, s_head, s_dep, edge_b, bar);
}

// Round 6
// 158.462 us; speedup vs baseline: 1.3976x; 1.3976x over previous
//
#include <hip/hip_runtime.h>
#include <hip/hip_bf16.h>
#include <stdint.h>

#define D_DIM 1024
#define B_DIM 8
#define S_DIM 1024

typedef __bf16 bf16;
typedef __bf16 bf16x4 __attribute__((ext_vector_type(4)));
typedef __bf16 bf16x8 __attribute__((ext_vector_type(8)));
typedef float floatx4 __attribute__((ext_vector_type(4)));

__device__ __forceinline__ void async_copy16(const void* g, void* l) {
    __builtin_amdgcn_global_load_lds(
        (const __attribute__((address_space(1))) void*)g,
        (__attribute__((address_space(3))) void*)l, 16, 0, 0);
}

// ---------------------------------------------------------------------------
// prep_du: cast dep fp32->bf16 (+ s_dep projection) and U fp32->bf16.
// Only the data GEMM1 needs — head cast rides inside the GEMM1 launch.
// blocks [0,1024): dep rows (4 rows/block, one wave per row).
// blocks [1024,1280): U rows (4 rows/block).
// ---------------------------------------------------------------------------
__global__ __launch_bounds__(256) void prep_du(
    const float* __restrict__ dep, const float* __restrict__ U,
    const float* __restrict__ edge_W,
    bf16* __restrict__ dep_b, bf16* __restrict__ U_b,
    float* __restrict__ s_dep)
{
    int blk  = blockIdx.x;
    int wid  = threadIdx.x >> 6;
    int lane = threadIdx.x & 63;

    if (blk < 1024) {
        int row = blk * 4 + wid;                 // 0..4095? no: 1024*4 = 4096
        // dep has 8192 rows; 1024 blocks * 4 waves... need 8192 waves.
        // -> use 2 rows per wave instead: row = blk*8 + wid*2 + rep
        const float* w2 = edge_W + D_DIM;
        #pragma unroll
        for (int rep = 0; rep < 2; ++rep) {
            int r = blk * 8 + wid * 2 + rep;     // 0..8191
            const float* src = dep   + (size_t)r * D_DIM;
            bf16*        dst = dep_b + (size_t)r * D_DIM;
            float d = 0.0f;
            #pragma unroll
            for (int it = 0; it < 4; ++it) {
                int idx = it * 64 + lane;
                float4 v  = ((const float4*)src)[idx];
                float4 wv = ((const float4*)w2)[idx];
                bf16x4 o;
                o[0] = (bf16)v.x; o[1] = (bf16)v.y; o[2] = (bf16)v.z; o[3] = (bf16)v.w;
                ((bf16x4*)dst)[idx] = o;
                d += v.x * wv.x + v.y * wv.y + v.z * wv.z + v.w * wv.w;
            }
            #pragma unroll
            for (int off = 32; off > 0; off >>= 1)
                d += __shfl_down(d, off, 64);
            if (lane == 0) s_dep[r] = d;
        }
    } else {
        int row = (blk - 1024) * 4 + wid;        // 0..1023
        const float* src = U   + (size_t)row * D_DIM;
        bf16*        dst = U_b + (size_t)row * D_DIM;
        #pragma unroll
        for (int it = 0; it < 4; ++it) {
            int idx = it * 64 + lane;
            float4 v = ((const float4*)src)[idx];
            bf16x4 o;
            o[0] = (bf16)v.x; o[1] = (bf16)v.y; o[2] = (bf16)v.z; o[3] = (bf16)v.w;
            ((bf16x4*)dst)[idx] = o;
        }
    }
}

// ---------------------------------------------------------------------------
// R1-verified GEMM core: 128x128 tile, BK=64, 512 thr (8 waves 2Mx4N,
// per-wave 64x32 = acc[4][2]). global_load_lds width-16 staging with
// XOR-swizzled source columns -> conflict-free ds_read_b128.
// ---------------------------------------------------------------------------
__device__ __forceinline__ void gemm_core(
    const bf16* __restrict__ Ab, const bf16* __restrict__ Bb,
    bf16* As, bf16* Bs, floatx4 (&acc)[4][2],
    int wid, int lane, int quad, int l16, int wr, int wc)
{
    for (int k0 = 0; k0 < D_DIM; k0 += 64) {
        #pragma unroll
        for (int it = 0; it < 2; ++it) {
            int g  = wid * 128 + it * 64 + lane;
            int r  = g >> 3;
            int cg = (g & 7) ^ (r & 7);              // XOR swizzle
            int ldsoff = (wid * 128 + it * 64) * 8;  // wave-uniform base
            async_copy16(Ab + (size_t)r * D_DIM + k0 + cg * 8, &As[ldsoff]);
            async_copy16(Bb + (size_t)r * D_DIM + k0 + cg * 8, &Bs[ldsoff]);
        }
        __syncthreads();   // staging complete

        #pragma unroll
        for (int kk = 0; kk < 64; kk += 32) {
            bf16x8 a[4], b[2];
            #pragma unroll
            for (int mt = 0; mt < 4; ++mt) {
                int row  = wr * 64 + mt * 16 + l16;
                int slot = ((kk >> 3) + quad) ^ (row & 7);
                a[mt] = *(const bf16x8*)&As[row * 64 + slot * 8];
            }
            #pragma unroll
            for (int nt = 0; nt < 2; ++nt) {
                int row  = wc * 32 + nt * 16 + l16;
                int slot = ((kk >> 3) + quad) ^ (row & 7);
                b[nt] = *(const bf16x8*)&Bs[row * 64 + slot * 8];
            }
            __builtin_amdgcn_s_setprio(1);
            #pragma unroll
            for (int mt = 0; mt < 4; ++mt)
                #pragma unroll
                for (int nt = 0; nt < 2; ++nt)
                    acc[mt][nt] = __builtin_amdgcn_mfma_f32_16x16x32_bf16(
                        a[mt], b[nt], acc[mt][nt], 0, 0, 0);
            __builtin_amdgcn_s_setprio(0);
        }
        __syncthreads();   // all reads done before next-iter staging
    }
}

// ---------------------------------------------------------------------------
// K1 launch (1536 blocks):
//   blocks [0,512):    GEMM1 tmpD = dep_b @ U_b^T (bijective XCD-chunk swz)
//   blocks [512,1536): cast head fp32->bf16 + s_head projection (GEMM1
//     never reads head_b, so no intra-launch ordering is needed; the cast
//     waves co-schedule into the spare occupancy and overlap GEMM1).
// ---------------------------------------------------------------------------
__global__ __launch_bounds__(512) void gemm1_kernel(
    const bf16* __restrict__ dep_b, const bf16* __restrict__ U_b,
    bf16* __restrict__ tmpD,
    const float* __restrict__ head, const float* __restrict__ edge_W,
    bf16* __restrict__ head_b, float* __restrict__ s_head)
{
    int tid  = threadIdx.x;
    int wid  = tid >> 6;
    int lane = tid & 63;

    if (blockIdx.x >= 512) {
        // ---- head cast + projection: 1024 blocks x 8 waves, 1 row/wave ----
        int row = (blockIdx.x - 512) * 8 + wid;       // 0..8191
        const float* src = head   + (size_t)row * D_DIM;
        bf16*        dst = head_b + (size_t)row * D_DIM;
        const float* w1  = edge_W;
        float d = 0.0f;
        #pragma unroll
        for (int it = 0; it < 4; ++it) {
            int idx = it * 64 + lane;
            float4 v  = ((const float4*)src)[idx];
            float4 wv = ((const float4*)w1)[idx];
            bf16x4 o;
            o[0] = (bf16)v.x; o[1] = (bf16)v.y; o[2] = (bf16)v.z; o[3] = (bf16)v.w;
            ((bf16x4*)dst)[idx] = o;
            d += v.x * wv.x + v.y * wv.y + v.z * wv.z + v.w * wv.w;
        }
        #pragma unroll
        for (int off = 32; off > 0; off >>= 1)
            d += __shfl_down(d, off, 64);
        if (lane == 0) s_head[row] = d;
        return;
    }

    // ---- GEMM1 ----
    __shared__ bf16 As[128 * 64];
    __shared__ bf16 Bs[128 * 64];

    int quad = lane >> 4;
    int l16  = lane & 15;
    int wr   = wid >> 2;   // 0..1
    int wc   = wid & 3;    // 0..3

    int lin = blockIdx.x;                    // 0..511
    int swz = (lin & 7) * 64 + (lin >> 3);   // bijective XCD-chunk
    int bx  = swz & 7;         // N-tile (U rows)
    int by  = swz >> 3;        // M-tile (dep rows)

    int tile_m = by * 128;
    int tile_n = bx * 128;
    const bf16* Ab = dep_b + (size_t)tile_m * D_DIM;
    const bf16* Bb = U_b   + (size_t)tile_n * D_DIM;

    floatx4 zero = {0.0f, 0.0f, 0.0f, 0.0f};
    floatx4 acc[4][2];
    #pragma unroll
    for (int i = 0; i < 4; ++i)
        #pragma unroll
        for (int j = 0; j < 2; ++j) acc[i][j] = zero;

    gemm_core(Ab, Bb, As, Bs, acc, wid, lane, quad, l16, wr, wc);

    int row0 = tile_m + wr * 64;
    int col0 = tile_n + wc * 32;
    #pragma unroll
    for (int mt = 0; mt < 4; ++mt)
        #pragma unroll
        for (int r = 0; r < 4; ++r) {
            int row = row0 + mt * 16 + quad * 4 + r;
            #pragma unroll
            for (int nt = 0; nt < 2; ++nt) {
                int col = col0 + nt * 16 + l16;
                tmpD[(size_t)row * D_DIM + col] = (bf16)acc[mt][nt][r];
            }
        }
}

// ---------------------------------------------------------------------------
// K2: out = head_b @ tmpD^T + s_head + s_dep + bias. 512 blocks.
// XCD-chunk decode keeps batch bz on XCD bz (head_b/tmpD 4 MB = its L2).
// ---------------------------------------------------------------------------
__global__ __launch_bounds__(512) void gemm2_kernel(
    const bf16* __restrict__ head_b, const bf16* __restrict__ tmpD,
    float* __restrict__ out,
    const float* __restrict__ s_head, const float* __restrict__ s_dep,
    const float* __restrict__ edge_b)
{
    __shared__ bf16 As[128 * 64];
    __shared__ bf16 Bs[128 * 64];

    int tid  = threadIdx.x;
    int wid  = tid >> 6;
    int lane = tid & 63;
    int quad = lane >> 4;
    int l16  = lane & 15;
    int wr   = wid >> 2;   // 0..1
    int wc   = wid & 3;    // 0..3

    int lin = blockIdx.x;                    // 0..511
    int swz = (lin & 7) * 64 + (lin >> 3);   // bijective XCD-chunk
    int bx  = swz & 7;         // tmpD j-tile
    int by  = (swz >> 3) & 7;  // head i-tile
    int bz  = swz >> 6;        // batch (aligned with XCD = lin&7)

    int tile_m = by * 128;
    int tile_n = bx * 128;
    const bf16* Ab = head_b + (size_t)bz * S_DIM * D_DIM + (size_t)tile_m * D_DIM;
    const bf16* Bb = tmpD   + (size_t)bz * S_DIM * D_DIM + (size_t)tile_n * D_DIM;

    floatx4 zero = {0.0f, 0.0f, 0.0f, 0.0f};
    floatx4 acc[4][2];
    #pragma unroll
    for (int i = 0; i < 4; ++i)
        #pragma unroll
        for (int j = 0; j < 2; ++j) acc[i][j] = zero;

    gemm_core(Ab, Bb, As, Bs, acc, wid, lane, quad, l16, wr, wc);

    float b0 = edge_b[0];
    const float* srow = s_head + (size_t)bz * S_DIM;
    const float* scol = s_dep  + (size_t)bz * S_DIM;
    float* Cf = out + (size_t)bz * S_DIM * S_DIM;
    int row0 = tile_m + wr * 64;
    int col0 = tile_n + wc * 32;
    #pragma unroll
    for (int mt = 0; mt < 4; ++mt)
        #pragma unroll
        for (int r = 0; r < 4; ++r) {
            int row = row0 + mt * 16 + quad * 4 + r;
            float sh = srow[row] + b0;
            #pragma unroll
            for (int nt = 0; nt < 2; ++nt) {
                int col = col0 + nt * 16 + l16;
                __builtin_nontemporal_store(acc[mt][nt][r] + sh + scol[col],
                                            &Cf[(size_t)row * S_DIM + col]);
            }
        }
}

// ---------------------------------------------------------------------------
// Chain (3 dispatches, prep split so only dep/U casting gates GEMM1):
//   1. prep_du:  dep_b, U_b, s_dep                   (~9 us)
//   2. gemm1:    tmpD = dep_b @ U_b^T  ||  head cast + s_head  (~35 us)
//   3. gemm2:    out = head_b @ tmpD^T + s_head + s_dep + bias (~30 us)
// ---------------------------------------------------------------------------
extern "C" void kernel_launch(void* const* d_in, const int* in_sizes, int n_in,
                              void* d_out, int out_size, void* d_ws, size_t ws_size,
                              hipStream_t stream) {
    const float* head   = (const float*)d_in[0];
    const float* dep    = (const float*)d_in[1];
    const float* edge_U = (const float*)d_in[2];
    const float* edge_W = (const float*)d_in[3];
    const float* edge_b = (const float*)d_in[4];
    float* out = (float*)d_out;

    char* ws = (char*)d_ws;
    const size_t nBSD = (size_t)B_DIM * S_DIM * D_DIM;

    bf16*  head_b = (bf16*)ws;  ws += nBSD * sizeof(bf16);
    bf16*  dep_b  = (bf16*)ws;  ws += nBSD * sizeof(bf16);
    bf16*  U_b    = (bf16*)ws;  ws += (size_t)D_DIM * D_DIM * sizeof(bf16);
    bf16*  tmpD   = (bf16*)ws;  ws += nBSD * sizeof(bf16);
    float* s_head = (float*)ws; ws += (size_t)B_DIM * S_DIM * sizeof(float);
    float* s_dep  = (float*)ws; ws += (size_t)B_DIM * S_DIM * sizeof(float);

    // 1. cast dep + U, s_dep projection (only what GEMM1 needs)
    prep_du<<<1024 + 256, 256, 0, stream>>>(
        dep, edge_U, edge_W, dep_b, U_b, s_dep);

    // 2. GEMM1 (512 blocks) + head cast / s_head (1024 blocks), one launch
    gemm1_kernel<<<1536, 512, 0, stream>>>(
        dep_b, U_b, tmpD, head, edge_W, head_b, s_head);

    // 3. GEMM2
    gemm2_kernel<<<512, 512, 0, stream>>>(
        head_b, tmpD, out, s_head, s_dep, edge_b);
}